// Round 4
// baseline (387.954 us; speedup 1.0000x reference)
//
#include <hip/hip_runtime.h>
#include <cstdint>
#include <cstddef>

// ============================================================================
// MechanismGrabber on MI355X (gfx950)
//
// selected[n,d] = sum_{m,e} a[n,m]*x[n,e]*Wm[m,d,e] + sum_m a[n,m]*(bm+cm)[m,d]
// == single GEMM: (N=32768) x (K=16448) x (D=256) with A generated on the fly.
//
// R3: big_gemm moved to v_mfma_f32_32x32x16_f16 (2382 TF ceiling vs 2075),
//     wave grid 1x8 (128x32 per wave -> no B-read duplication across waves,
//     CU LDS traffic 96->64 KB/chunk), B-fragments register-double-buffered
//     (prefetch q+1 under q's MFMAs, vmcnt(4) certifies q+1 at the barrier).
//     New Wcat fragment layout is conflict-free with NO swizzle.
// ============================================================================

typedef _Float16 f16;
typedef f16 f16x8 __attribute__((ext_vector_type(8)));
typedef float f32x4 __attribute__((ext_vector_type(4)));
typedef float f32x16 __attribute__((ext_vector_type(16)));

#define DEV __device__ __forceinline__

DEV uint32_t swz128(uint32_t b) { return b ^ (((b >> 7) & 7u) << 4); }

DEV void gload_lds16(const void* g, void* l) {
  __builtin_amdgcn_global_load_lds(
      (const __attribute__((address_space(1))) unsigned int*)g,
      (__attribute__((address_space(3))) unsigned int*)l, 16, 0, 0);
}

DEV f16x8 cvt8(float4 u0, float4 u1) {
  f16x8 v = {(f16)u0.x, (f16)u0.y, (f16)u0.z, (f16)u0.w,
             (f16)u1.x, (f16)u1.y, (f16)u1.z, (f16)u1.w};
  return v;
}

// ---------------------------------------------------------------------------
// prep for gemm_tpl (16x16x32 path, selector/integrate): unchanged swizzled
// fragment layout.
// ---------------------------------------------------------------------------
__global__ void prep_b_kernel(const float* __restrict__ S, f16* __restrict__ dst,
                              int K, int BN, int total) {
  int t = blockIdx.x * 256 + threadIdx.x;
  if (t >= total) return;
  int gpc = BN * 8;
  int g = t % gpc;
  int c = (t / gpc) % (K / 64);
  int cb = t / (gpc * (K / 64));
  int ks = g / (BN * 4);
  int rem = g % (BN * 4);
  int col = rem >> 2;
  int kg = rem & 3;
  int J = cb * BN + col;
  int k = c * 64 + ks * 32 + kg * 8;
  const float* s = S + (size_t)J * K + k;
  float4 u0 = *(const float4*)s;
  float4 u1 = *(const float4*)(s + 4);
  f16* chunk = dst + (size_t)(cb * (K / 64) + c) * (BN * 64);
  *(f16x8*)((char*)chunk + swz128((uint32_t)g * 16)) = cvt8(u0, u1);
}

// ---------------------------------------------------------------------------
// Wcat (32x32x16 B-fragment layout, LINEAR/no-swizzle): 257 chunks of 64x256.
// Within a chunk: group g = (kstep*2 + khalf)*256 + col, holds B[k][col] for
// k = kstep*16 + khalf*8 + (0..7), at byte offset g*16.
// Chunk c in 0..255: er=c>>6, m=c&63; value[k][col] = Wm[m][col][er*64+k].
// Chunk 256: value[k][col] = bm[k][col]+cm[k][col].
// ---------------------------------------------------------------------------
__global__ void prep_wcat_kernel(const float* __restrict__ Wm,
                                 const float* __restrict__ bm,
                                 const float* __restrict__ cm,
                                 f16* __restrict__ dst) {
  int t = blockIdx.x * 256 + threadIdx.x;
  if (t >= 257 * 2048) return;
  int g = t & 2047;
  int c = t >> 11;
  int kstep = g >> 9;          // 0..3
  int khalf = (g >> 8) & 1;    // 0..1
  int col = g & 255;
  int k0 = kstep * 16 + khalf * 8;
  f16x8 v;
  if (c < 256) {
    int m = c & 63;
    int e0 = (c >> 6) * 64 + k0;
    const float* s = Wm + ((size_t)m * 256 + col) * 256 + e0;
    float4 u0 = *(const float4*)s;
    float4 u1 = *(const float4*)(s + 4);
    v = cvt8(u0, u1);
  } else {
#pragma unroll
    for (int j = 0; j < 8; ++j) {
      int k = k0 + j;
      v[j] = (f16)(bm[k * 256 + col] + cm[k * 256 + col]);
    }
  }
  *(f16x8*)(dst + (size_t)c * 16384 + (size_t)g * 8) = v;
}

// ---------------------------------------------------------------------------
// Generic MFMA GEMM (selector + integrate phases). Unchanged.
// ---------------------------------------------------------------------------
template <int BN, int NCHUNK, int A0C, int EPI>
__global__ __launch_bounds__(BN == 256 ? 512 : 256, 2)
void gemm_tpl(const float* __restrict__ A0, int lda0,
              const f16* __restrict__ A1, int lda1,
              const f16* __restrict__ Bt,
              const float* __restrict__ bias,
              float* __restrict__ outF, f16* __restrict__ outH, int ldo) {
  constexpr int WAVES = (BN == 256) ? 8 : 4;
  constexpr int THREADS = WAVES * 64;
  constexpr int WC = (BN == 256) ? 4 : 1;
  constexpr int WR = WAVES / WC;
  constexpr int RT = 128 / (WR * 16);
  constexpr int CT = (BN / WC) / 16;

  __shared__ alignas(16) f16 sA[2][128 * 64];
  __shared__ alignas(16) f16 sB[2][BN * 64];

  const int tid = threadIdx.x;
  const int lane = tid & 63;
  const int wid = tid >> 6;
  const int wr = wid / WC, wc = wid % WC;
  const int rb = blockIdx.x, cb = blockIdx.y;

  auto stageB = [&](int c, int buf) {
    const char* src = (const char*)(Bt + (size_t)(cb * NCHUNK + c) * (BN * 64));
#pragma unroll
    for (int it = 0; it < (BN * 64 * 2) / (THREADS * 16); ++it) {
      int off = (it * THREADS + tid) * 16;
      gload_lds16(src + off, (char*)&sB[buf][0] + off);
    }
  };
  auto stageA = [&](int c, int buf) {
#pragma unroll
    for (int it = 0; it < 1024 / THREADS; ++it) {
      int gg = it * THREADS + tid;
      int row = gg >> 3, eg = gg & 7;
      size_t rowG = (size_t)rb * 128 + row;
      f16x8 v;
      if (A0C > 0 && c < A0C) {
        const float* s = A0 + rowG * lda0 + c * 64 + eg * 8;
        float4 u0 = *(const float4*)s;
        float4 u1 = *(const float4*)(s + 4);
        v = cvt8(u0, u1);
      } else {
        v = *(const f16x8*)(A1 + rowG * lda1 + (c - A0C) * 64 + eg * 8);
      }
      *(f16x8*)((char*)&sA[buf][0] + swz128((uint32_t)(row * 128 + eg * 16))) = v;
    }
  };

  f32x4 acc[RT][CT];
#pragma unroll
  for (int i = 0; i < RT; ++i)
#pragma unroll
    for (int j = 0; j < CT; ++j) acc[i][j] = (f32x4){0.f, 0.f, 0.f, 0.f};

  stageB(0, 0);
  stageA(0, 0);
  __syncthreads();

  for (int c = 0; c < NCHUNK; ++c) {
    int cur = c & 1;
    if (c + 1 < NCHUNK) {
      stageB(c + 1, cur ^ 1);
      stageA(c + 1, cur ^ 1);
    }
#pragma unroll
    for (int ks = 0; ks < 2; ++ks) {
      f16x8 af[RT], bf[CT];
#pragma unroll
      for (int rt = 0; rt < RT; ++rt) {
        int row = wr * (RT * 16) + rt * 16 + (lane & 15);
        af[rt] = *(const f16x8*)((const char*)&sA[cur][0] +
                                 swz128((uint32_t)(row * 128 + ks * 64 + (lane >> 4) * 16)));
      }
#pragma unroll
      for (int ct = 0; ct < CT; ++ct) {
        int col = wc * (CT * 16) + ct * 16 + (lane & 15);
        bf[ct] = *(const f16x8*)((const char*)&sB[cur][0] +
                                 swz128((uint32_t)(((ks * BN + col) * 4 + (lane >> 4)) * 16)));
      }
#pragma unroll
      for (int rt = 0; rt < RT; ++rt)
#pragma unroll
        for (int ct = 0; ct < CT; ++ct)
          acc[rt][ct] = __builtin_amdgcn_mfma_f32_16x16x32_f16(af[rt], bf[ct], acc[rt][ct], 0, 0, 0);
    }
    __syncthreads();
  }

#pragma unroll
  for (int rt = 0; rt < RT; ++rt)
#pragma unroll
    for (int ct = 0; ct < CT; ++ct)
#pragma unroll
      for (int i = 0; i < 4; ++i) {
        size_t row = (size_t)rb * 128 + wr * (RT * 16) + rt * 16 + (lane >> 4) * 4 + i;
        int colG = cb * BN + wc * (CT * 16) + ct * 16 + (lane & 15);
        float v = acc[rt][ct][i];
        if constexpr (EPI == 0) {
          if (bias) v += bias[colG];
          outF[row * ldo + colG] = v;
        } else {
          v += bias[colG];
          float ge = 0.5f * v * (1.0f + erff(v * 0.70710678118f));
          outH[row * ldo + colG] = (f16)ge;
        }
      }
}

// ---------------------------------------------------------------------------
// selector finish: a16[n,m] = softmax(logits+b2)[m] * sigmoid(glog+vm)[m]
// ---------------------------------------------------------------------------
__global__ void selector_finish(const float* __restrict__ logits,
                                const float* __restrict__ glog,
                                const float* __restrict__ b2,
                                const float* __restrict__ vm,
                                f16* __restrict__ a16) {
  int n = blockIdx.x * 4 + (threadIdx.x >> 6);
  int m = threadIdx.x & 63;
  float l = logits[(size_t)n * 64 + m] + b2[m];
  float mx = l;
#pragma unroll
  for (int o = 32; o; o >>= 1) mx = fmaxf(mx, __shfl_xor(mx, o));
  float p = expf(l - mx);
  float s = p;
#pragma unroll
  for (int o = 32; o; o >>= 1) s += __shfl_xor(s, o);
  float g = glog[(size_t)n * 64 + m] + vm[m];
  float gate = 1.0f / (1.0f + expf(-g));
  a16[(size_t)n * 64 + m] = (f16)(p / s * gate);
}

// ---------------------------------------------------------------------------
// big_gemm v3: 32x32x16 MFMA, wave grid 1x8 (128 rows x 32 cols per wave),
// 4-deep ring, 1 barrier/chunk, reg-double-buffered B fragments.
//
// Fragment layouts (32x32x16_f16, derived from verified 16x16x32 by the
// double-K-contiguous rule): A: row=lane&31, k=(lane>>5)*8+j;
// B: col=lane&31, k=(lane>>5)*8+j; C/D: col=lane&31,
// row=(reg&3)+8*(reg>>2)+4*(lane>>5).
//
// Per iter q: vmcnt(4) [chunk q+1 landed locally] -> barrier [globally]
// -> stage(q+3) -> prefetch bf(q+1) -> 16 MFMA on bf(q) (setprio).
// ---------------------------------------------------------------------------
__global__ __launch_bounds__(512, 2)
void big_gemm(const float* __restrict__ x, const f16* __restrict__ a16,
              const f16* __restrict__ Wcat, f16* __restrict__ sel) {
  __shared__ alignas(16) f16 sB[4][256 * 64];   // 4 x 32 KB ring
  __shared__ alignas(16) f16 sAa[128 * 72];     // 18 KB, row stride 144 B

  const int tid = threadIdx.x;
  const int lane = tid & 63;
  const int wid = tid >> 6;        // 0..7 -> col block (wid*32)
  const int l31 = lane & 31;
  const int khalf = lane >> 5;     // 0..1
  const int rb = blockIdx.x;

  auto stageB = [&](int c, int buf) {
    const char* src = (const char*)(Wcat + (size_t)c * 16384);
#pragma unroll
    for (int it = 0; it < 4; ++it) {
      int off = (it * 512 + tid) * 16;
      gload_lds16(src + off, (char*)&sB[buf][0] + off);
    }
  };

  // stage a -> sAa (row stride 144 B)
#pragma unroll
  for (int it = 0; it < 2; ++it) {
    int gg = it * 512 + tid;
    int row = gg >> 3, mg = gg & 7;
    f16x8 v = *(const f16x8*)(a16 + ((size_t)rb * 128 + row) * 64 + mg * 8);
    *(f16x8*)((char*)sAa + row * 144 + mg * 16) = v;
  }
  stageB(0, 0);
  stageB(1, 1);
  stageB(2, 2);
  asm volatile("s_waitcnt vmcnt(8) lgkmcnt(0)" ::: "memory");  // chunk0 + sAa done
  __builtin_amdgcn_s_barrier();
  __builtin_amdgcn_sched_barrier(0);

  f32x16 acc[4];
#pragma unroll
  for (int rt = 0; rt < 4; ++rt)
#pragma unroll
    for (int r = 0; r < 16; ++r) acc[rt][r] = 0.f;

  // x fragments in VGPRs: rows rt*32+l31, e = er*64 + ks*16 + khalf*8 + j
  f16x8 xv[4][4];
  auto loadXV = [&](int er) {
#pragma unroll
    for (int rt = 0; rt < 4; ++rt)
#pragma unroll
      for (int ks = 0; ks < 4; ++ks) {
        const float* s = x + ((size_t)rb * 128 + rt * 32 + l31) * 256
                           + er * 64 + ks * 16 + khalf * 8;
        float4 u0 = *(const float4*)s;
        float4 u1 = *(const float4*)(s + 4);
        xv[rt][ks] = cvt8(u0, u1);
      }
  };

  // per-lane B offset within a chunk: (kstep*2+khalf)*256 + col, col=wid*32+l31
  const int bOff = khalf * 4096 + wid * 512 + l31 * 16;

  f16x8 bf[2][4];
#pragma unroll
  for (int ks = 0; ks < 4; ++ks)
    bf[0][ks] = *(const f16x8*)((const char*)&sB[0][0] + bOff + ks * 8192);

  for (int q8 = 0; q8 < 256; q8 += 8) {
    if ((q8 & 63) == 0) loadXV(q8 >> 6);
    f16x8 as8[4];
#pragma unroll
    for (int rt = 0; rt < 4; ++rt)
      as8[rt] = *(const f16x8*)((const char*)sAa + (rt * 32 + l31) * 144 + (q8 & 63) * 2);
#pragma unroll
    for (int u = 0; u < 8; ++u) {
      const int q = q8 + u;
      asm volatile("s_waitcnt vmcnt(4)" ::: "memory");  // chunk q+1 landed (locally)
      __builtin_amdgcn_s_barrier();                      // ... and globally
      __builtin_amdgcn_sched_barrier(0);
      stageB(q + 3, (u + 3) & 3);
      // prefetch next chunk's B fragments (certified by this barrier)
      const char* nb = (const char*)&sB[(u + 1) & 3][0] + bOff;
#pragma unroll
      for (int ks = 0; ks < 4; ++ks)
        bf[(u + 1) & 1][ks] = *(const f16x8*)(nb + ks * 8192);
      __builtin_amdgcn_s_setprio(1);
#pragma unroll
      for (int ks = 0; ks < 4; ++ks) {
#pragma unroll
        for (int rt = 0; rt < 4; ++rt) {
          f16x8 af = xv[rt][ks] * as8[rt][u];
          acc[rt] = __builtin_amdgcn_mfma_f32_32x32x16_f16(af, bf[u & 1][ks], acc[rt], 0, 0, 0);
        }
      }
      __builtin_amdgcn_s_setprio(0);
    }
  }

  // bias chunk (q=256): B frags already in bf[0] (prefetched at u=7);
  // A = a[row, k] read from sAa (stable since prologue).
#pragma unroll
  for (int ks = 0; ks < 4; ++ks) {
#pragma unroll
    for (int rt = 0; rt < 4; ++rt) {
      f16x8 af = *(const f16x8*)((const char*)sAa + (rt * 32 + l31) * 144
                                 + ks * 32 + khalf * 16);
      acc[rt] = __builtin_amdgcn_mfma_f32_32x32x16_f16(af, bf[0][ks], acc[rt], 0, 0, 0);
    }
  }

  // store: col = wid*32+l31; row = rt*32 + (r&3)+8*(r>>2)+4*khalf
#pragma unroll
  for (int rt = 0; rt < 4; ++rt)
#pragma unroll
    for (int r = 0; r < 16; ++r) {
      int rowin = (r & 3) + 8 * (r >> 2) + 4 * khalf;
      size_t row = (size_t)rb * 128 + rt * 32 + rowin;
      sel[row * 256 + wid * 32 + l31] = (f16)acc[rt][r];
    }
}

// ---------------------------------------------------------------------------
extern "C" void kernel_launch(void* const* d_in, const int* in_sizes, int n_in,
                              void* d_out, int out_size, void* d_ws, size_t ws_size,
                              hipStream_t stream) {
  (void)in_sizes; (void)n_in; (void)out_size;
  const float* x   = (const float*)d_in[0];
  const float* ctx = (const float*)d_in[1];
  const float* Wm  = (const float*)d_in[2];
  const float* bm  = (const float*)d_in[3];
  const float* cm  = (const float*)d_in[4];
  const float* um  = (const float*)d_in[5];
  const float* vm  = (const float*)d_in[6];
  const float* W1  = (const float*)d_in[7];
  const float* b1  = (const float*)d_in[8];
  const float* W2  = (const float*)d_in[9];
  const float* b2  = (const float*)d_in[10];
  const float* Wi  = (const float*)d_in[11];
  const float* bi  = (const float*)d_in[12];
  float* out = (float*)d_out;

  char* ws = (char*)d_ws;
  size_t off = 0;
  // 260 chunk slots: 257 real + dummy tail (staged but never computed)
  f16* Wcat = (f16*)(ws + off); off += (size_t)260 * 16384 * 2;
  f16* W1t  = (f16*)(ws + off); off += (size_t)512 * 256 * 2;
  f16* W2t  = (f16*)(ws + off); off += (size_t)64 * 512 * 2;
  f16* umt  = (f16*)(ws + off); off += (size_t)64 * 256 * 2;
  f16* Wit  = (f16*)(ws + off); off += (size_t)256 * 512 * 2;
  f16* h16  = (f16*)(ws + off); off += (size_t)32768 * 512 * 2;
  float* logits = (float*)(ws + off); off += (size_t)32768 * 64 * 4;
  float* glog   = (float*)(ws + off); off += (size_t)32768 * 64 * 4;
  f16* a16   = (f16*)(ws + off); off += (size_t)32768 * 64 * 2;
  f16* sel16 = (f16*)(ws + off); off += (size_t)32768 * 256 * 2;
  if (ws_size < off) return;

  // ---- weight prep ----
  prep_wcat_kernel<<<dim3(257 * 2048 / 256), dim3(256), 0, stream>>>(Wm, bm, cm, Wcat);
  prep_b_kernel<<<dim3(16384 / 256), dim3(256), 0, stream>>>(W1, W1t, 256, 256, 16384);
  prep_b_kernel<<<dim3(4096 / 256),  dim3(256), 0, stream>>>(W2, W2t, 512, 64, 4096);
  prep_b_kernel<<<dim3(2048 / 256),  dim3(256), 0, stream>>>(um, umt, 256, 64, 2048);
  prep_b_kernel<<<dim3(16384 / 256), dim3(256), 0, stream>>>(Wi, Wit, 512, 256, 16384);

  // ---- phase A: selector ----
  gemm_tpl<256, 4, 4, 1><<<dim3(256, 2), dim3(512), 0, stream>>>(
      ctx, 256, nullptr, 0, W1t, b1, nullptr, h16, 512);
  gemm_tpl<64, 4, 4, 0><<<dim3(256, 1), dim3(256), 0, stream>>>(
      x, 256, nullptr, 0, umt, nullptr, glog, nullptr, 64);
  gemm_tpl<64, 8, 0, 0><<<dim3(256, 1), dim3(256), 0, stream>>>(
      nullptr, 0, h16, 512, W2t, nullptr, logits, nullptr, 64);
  selector_finish<<<dim3(32768 / 4), dim3(256), 0, stream>>>(logits, glog, b2, vm, a16);

  // ---- phase B: the 275-GFLOP contraction ----
  big_gemm<<<dim3(256), dim3(512), 0, stream>>>(x, a16, Wcat, sel16);

  // ---- phase C: integrate([x, selected]) ----
  gemm_tpl<256, 8, 4, 0><<<dim3(256, 1), dim3(512), 0, stream>>>(
      x, 256, sel16, 256, Wit, bi, out, nullptr, 256);
}

// Round 5
// 355.250 us; speedup vs baseline: 1.0921x; 1.0921x over previous
//
#include <hip/hip_runtime.h>
#include <cstdint>
#include <cstddef>

// ============================================================================
// MechanismGrabber on MI355X (gfx950)
//
// selected[n,d] = sum_{m,e} a[n,m]*x[n,e]*Wm[m,d,e] + sum_m a[n,m]*(bm+cm)[m,d]
// == single GEMM: (N=32768) x (K=16448) x (D=256) with A generated on the fly.
//
// R4: 2 blocks/CU for cross-block stall covering. Block = 256 thr (2x2 waves),
//     tile 128x128, Wcat split into 16KB per-col-half sub-chunks, 3-slot LDS
//     ring (66KB/block). Wave tile 64x64 (ct=2 shares af -> VALU halved).
//     32x32x16 MFMA, reg-dbuf B-frags, counted vmcnt(4), 1 barrier/chunk.
// ============================================================================

typedef _Float16 f16;
typedef f16 f16x8 __attribute__((ext_vector_type(8)));
typedef float f32x4 __attribute__((ext_vector_type(4)));
typedef float f32x16 __attribute__((ext_vector_type(16)));

#define DEV __device__ __forceinline__

DEV uint32_t swz128(uint32_t b) { return b ^ (((b >> 7) & 7u) << 4); }

DEV void gload_lds16(const void* g, void* l) {
  __builtin_amdgcn_global_load_lds(
      (const __attribute__((address_space(1))) unsigned int*)g,
      (__attribute__((address_space(3))) unsigned int*)l, 16, 0, 0);
}

DEV f16x8 cvt8(float4 u0, float4 u1) {
  f16x8 v = {(f16)u0.x, (f16)u0.y, (f16)u0.z, (f16)u0.w,
             (f16)u1.x, (f16)u1.y, (f16)u1.z, (f16)u1.w};
  return v;
}

// ---------------------------------------------------------------------------
// prep for gemm_tpl (16x16x32 path, selector/integrate): unchanged.
// ---------------------------------------------------------------------------
__global__ void prep_b_kernel(const float* __restrict__ S, f16* __restrict__ dst,
                              int K, int BN, int total) {
  int t = blockIdx.x * 256 + threadIdx.x;
  if (t >= total) return;
  int gpc = BN * 8;
  int g = t % gpc;
  int c = (t / gpc) % (K / 64);
  int cb = t / (gpc * (K / 64));
  int ks = g / (BN * 4);
  int rem = g % (BN * 4);
  int col = rem >> 2;
  int kg = rem & 3;
  int J = cb * BN + col;
  int k = c * 64 + ks * 32 + kg * 8;
  const float* s = S + (size_t)J * K + k;
  float4 u0 = *(const float4*)s;
  float4 u1 = *(const float4*)(s + 4);
  f16* chunk = dst + (size_t)(cb * (K / 64) + c) * (BN * 64);
  *(f16x8*)((char*)chunk + swz128((uint32_t)g * 16)) = cvt8(u0, u1);
}

// ---------------------------------------------------------------------------
// Wcat v2: [cb in 0..1][c in 0..259] sub-chunks of 64k x 128col = 16 KB.
// Within a sub-chunk: group g = kstep*256 + khalf*128 + col128, byte g*16,
// holds B[k][col] for k = kstep*16 + khalf*8 + (0..7), col = cb*128+col128.
// c in 0..255: er=c>>6, m=c&63; value[k][col] = Wm[m][col][er*64+k].
// c==256: value[k][col] = bm[k][col]+cm[k][col].  c>=257: dummy (never read).
// ---------------------------------------------------------------------------
__global__ void prep_wcat_kernel(const float* __restrict__ Wm,
                                 const float* __restrict__ bm,
                                 const float* __restrict__ cm,
                                 f16* __restrict__ dst) {
  int t = blockIdx.x * 256 + threadIdx.x;
  if (t >= 2 * 257 * 1024) return;
  int g = t & 1023;
  int c = (t >> 10) % 257;
  int cb = t / (257 * 1024);
  int kstep = g >> 8;          // 0..3
  int khalf = (g >> 7) & 1;    // 0..1
  int col = cb * 128 + (g & 127);
  int k0 = kstep * 16 + khalf * 8;
  f16x8 v;
  if (c < 256) {
    int m = c & 63;
    int e0 = (c >> 6) * 64 + k0;
    const float* s = Wm + ((size_t)m * 256 + col) * 256 + e0;
    float4 u0 = *(const float4*)s;
    float4 u1 = *(const float4*)(s + 4);
    v = cvt8(u0, u1);
  } else {
#pragma unroll
    for (int j = 0; j < 8; ++j) {
      int k = k0 + j;
      v[j] = (f16)(bm[k * 256 + col] + cm[k * 256 + col]);
    }
  }
  *(f16x8*)(dst + ((size_t)(cb * 260 + c)) * 8192 + (size_t)g * 8) = v;
}

// ---------------------------------------------------------------------------
// Generic MFMA GEMM (selector + integrate phases). Unchanged.
// ---------------------------------------------------------------------------
template <int BN, int NCHUNK, int A0C, int EPI>
__global__ __launch_bounds__(BN == 256 ? 512 : 256, 2)
void gemm_tpl(const float* __restrict__ A0, int lda0,
              const f16* __restrict__ A1, int lda1,
              const f16* __restrict__ Bt,
              const float* __restrict__ bias,
              float* __restrict__ outF, f16* __restrict__ outH, int ldo) {
  constexpr int WAVES = (BN == 256) ? 8 : 4;
  constexpr int THREADS = WAVES * 64;
  constexpr int WC = (BN == 256) ? 4 : 1;
  constexpr int WR = WAVES / WC;
  constexpr int RT = 128 / (WR * 16);
  constexpr int CT = (BN / WC) / 16;

  __shared__ alignas(16) f16 sA[2][128 * 64];
  __shared__ alignas(16) f16 sB[2][BN * 64];

  const int tid = threadIdx.x;
  const int lane = tid & 63;
  const int wid = tid >> 6;
  const int wr = wid / WC, wc = wid % WC;
  const int rb = blockIdx.x, cb = blockIdx.y;

  auto stageB = [&](int c, int buf) {
    const char* src = (const char*)(Bt + (size_t)(cb * NCHUNK + c) * (BN * 64));
#pragma unroll
    for (int it = 0; it < (BN * 64 * 2) / (THREADS * 16); ++it) {
      int off = (it * THREADS + tid) * 16;
      gload_lds16(src + off, (char*)&sB[buf][0] + off);
    }
  };
  auto stageA = [&](int c, int buf) {
#pragma unroll
    for (int it = 0; it < 1024 / THREADS; ++it) {
      int gg = it * THREADS + tid;
      int row = gg >> 3, eg = gg & 7;
      size_t rowG = (size_t)rb * 128 + row;
      f16x8 v;
      if (A0C > 0 && c < A0C) {
        const float* s = A0 + rowG * lda0 + c * 64 + eg * 8;
        float4 u0 = *(const float4*)s;
        float4 u1 = *(const float4*)(s + 4);
        v = cvt8(u0, u1);
      } else {
        v = *(const f16x8*)(A1 + rowG * lda1 + (c - A0C) * 64 + eg * 8);
      }
      *(f16x8*)((char*)&sA[buf][0] + swz128((uint32_t)(row * 128 + eg * 16))) = v;
    }
  };

  f32x4 acc[RT][CT];
#pragma unroll
  for (int i = 0; i < RT; ++i)
#pragma unroll
    for (int j = 0; j < CT; ++j) acc[i][j] = (f32x4){0.f, 0.f, 0.f, 0.f};

  stageB(0, 0);
  stageA(0, 0);
  __syncthreads();

  for (int c = 0; c < NCHUNK; ++c) {
    int cur = c & 1;
    if (c + 1 < NCHUNK) {
      stageB(c + 1, cur ^ 1);
      stageA(c + 1, cur ^ 1);
    }
#pragma unroll
    for (int ks = 0; ks < 2; ++ks) {
      f16x8 af[RT], bf[CT];
#pragma unroll
      for (int rt = 0; rt < RT; ++rt) {
        int row = wr * (RT * 16) + rt * 16 + (lane & 15);
        af[rt] = *(const f16x8*)((const char*)&sA[cur][0] +
                                 swz128((uint32_t)(row * 128 + ks * 64 + (lane >> 4) * 16)));
      }
#pragma unroll
      for (int ct = 0; ct < CT; ++ct) {
        int col = wc * (CT * 16) + ct * 16 + (lane & 15);
        bf[ct] = *(const f16x8*)((const char*)&sB[cur][0] +
                                 swz128((uint32_t)(((ks * BN + col) * 4 + (lane >> 4)) * 16)));
      }
#pragma unroll
      for (int rt = 0; rt < RT; ++rt)
#pragma unroll
        for (int ct = 0; ct < CT; ++ct)
          acc[rt][ct] = __builtin_amdgcn_mfma_f32_16x16x32_f16(af[rt], bf[ct], acc[rt][ct], 0, 0, 0);
    }
    __syncthreads();
  }

#pragma unroll
  for (int rt = 0; rt < RT; ++rt)
#pragma unroll
    for (int ct = 0; ct < CT; ++ct)
#pragma unroll
      for (int i = 0; i < 4; ++i) {
        size_t row = (size_t)rb * 128 + wr * (RT * 16) + rt * 16 + (lane >> 4) * 4 + i;
        int colG = cb * BN + wc * (CT * 16) + ct * 16 + (lane & 15);
        float v = acc[rt][ct][i];
        if constexpr (EPI == 0) {
          if (bias) v += bias[colG];
          outF[row * ldo + colG] = v;
        } else {
          v += bias[colG];
          float ge = 0.5f * v * (1.0f + erff(v * 0.70710678118f));
          outH[row * ldo + colG] = (f16)ge;
        }
      }
}

// ---------------------------------------------------------------------------
// selector finish: a16[n,m] = softmax(logits+b2)[m] * sigmoid(glog+vm)[m]
// ---------------------------------------------------------------------------
__global__ void selector_finish(const float* __restrict__ logits,
                                const float* __restrict__ glog,
                                const float* __restrict__ b2,
                                const float* __restrict__ vm,
                                f16* __restrict__ a16) {
  int n = blockIdx.x * 4 + (threadIdx.x >> 6);
  int m = threadIdx.x & 63;
  float l = logits[(size_t)n * 64 + m] + b2[m];
  float mx = l;
#pragma unroll
  for (int o = 32; o; o >>= 1) mx = fmaxf(mx, __shfl_xor(mx, o));
  float p = expf(l - mx);
  float s = p;
#pragma unroll
  for (int o = 32; o; o >>= 1) s += __shfl_xor(s, o);
  float g = glog[(size_t)n * 64 + m] + vm[m];
  float gate = 1.0f / (1.0f + expf(-g));
  a16[(size_t)n * 64 + m] = (f16)(p / s * gate);
}

// ---------------------------------------------------------------------------
// big_gemm v4: 256 threads (2x2 waves), block tile 128x128, wave tile 64x64
// (32x32x16 MFMA: rt=2, ct=2 -> af shared by ct). 3-slot 16KB LDS ring,
// 2 blocks/CU. Per iter: stage(q+2,p2) -> vmcnt(4) -> barrier -> prefetch
// bf(q+1) from p1 -> 16 MFMA on bf(q) regs -> rotate ring.
// ---------------------------------------------------------------------------
__global__ __launch_bounds__(256, 2)
void big_gemm(const float* __restrict__ x, const f16* __restrict__ a16,
              const f16* __restrict__ Wcat, f16* __restrict__ sel) {
  __shared__ alignas(16) f16 sB[3][128 * 64];   // 3 x 16 KB ring
  __shared__ alignas(16) f16 sAa[128 * 72];     // 18 KB, row stride 144 B

  const int tid = threadIdx.x;
  const int lane = tid & 63;
  const int wid = tid >> 6;          // 0..3
  const int wr = wid >> 1, wc = wid & 1;
  const int l31 = lane & 31;
  const int khalf = lane >> 5;       // 0..1
  const int rb = blockIdx.x, cb = blockIdx.y;
  const f16* Wb = Wcat + (size_t)cb * 260 * 8192;

  auto stageTo = [&](int c, char* dstLds) {
    const char* src = (const char*)(Wb + (size_t)c * 8192);
#pragma unroll
    for (int it = 0; it < 4; ++it) {
      int off = (it * 256 + tid) * 16;
      gload_lds16(src + off, dstLds + off);
    }
  };

  // stage a -> sAa (1024 groups / 256 thr = 4 each)
#pragma unroll
  for (int it = 0; it < 4; ++it) {
    int gg = it * 256 + tid;
    int row = gg >> 3, mg = gg & 7;
    f16x8 v = *(const f16x8*)(a16 + ((size_t)rb * 128 + row) * 64 + mg * 8);
    *(f16x8*)((char*)sAa + row * 144 + mg * 16) = v;
  }
  char* p0 = (char*)&sB[0][0];
  char* p1 = (char*)&sB[1][0];
  char* p2 = (char*)&sB[2][0];
  stageTo(0, p0);
  stageTo(1, p1);
  asm volatile("s_waitcnt vmcnt(4) lgkmcnt(0)" ::: "memory");  // chunk0 + sAa done
  __builtin_amdgcn_s_barrier();
  __builtin_amdgcn_sched_barrier(0);

  // per-lane B offset within a 16KB sub-chunk (linear, conflict-free):
  // byte = kstep*4096 + khalf*2048 + (wc*64 + ct*32 + l31)*16
  const int bOff = khalf * 2048 + wc * 1024 + l31 * 16;

  f32x16 acc[2][2];
#pragma unroll
  for (int i = 0; i < 2; ++i)
#pragma unroll
    for (int j = 0; j < 2; ++j)
#pragma unroll
      for (int r = 0; r < 16; ++r) acc[i][j][r] = 0.f;

  f16x8 bf[2][8];
#pragma unroll
  for (int ks = 0; ks < 4; ++ks)
#pragma unroll
    for (int ct = 0; ct < 2; ++ct)
      bf[0][ks * 2 + ct] = *(const f16x8*)(p0 + bOff + ks * 4096 + ct * 512);

  f16x8 xv[2][4];
  auto loadXV = [&](int er) {
#pragma unroll
    for (int rt = 0; rt < 2; ++rt)
#pragma unroll
      for (int ks = 0; ks < 4; ++ks) {
        const float* s = x + ((size_t)rb * 128 + wr * 64 + rt * 32 + l31) * 256
                           + er * 64 + ks * 16 + khalf * 8;
        float4 u0 = *(const float4*)s;
        float4 u1 = *(const float4*)(s + 4);
        xv[rt][ks] = cvt8(u0, u1);
      }
  };

  for (int q8 = 0; q8 < 256; q8 += 8) {
    if ((q8 & 63) == 0) loadXV(q8 >> 6);
    f16x8 as8[2];
#pragma unroll
    for (int rt = 0; rt < 2; ++rt)
      as8[rt] = *(const f16x8*)((const char*)sAa + (wr * 64 + rt * 32 + l31) * 144 + (q8 & 63) * 2);
#pragma unroll
    for (int u = 0; u < 8; ++u) {
      const int q = q8 + u;
      stageTo(q + 2, p2);
      asm volatile("s_waitcnt vmcnt(4)" ::: "memory");  // chunk q+1 landed (own loads)
      __builtin_amdgcn_s_barrier();                      // ... all waves'
      __builtin_amdgcn_sched_barrier(0);
      // prefetch next chunk's B fragments from p1 (certified by the barrier)
      const char* nb = p1 + bOff;
#pragma unroll
      for (int ks = 0; ks < 4; ++ks)
#pragma unroll
        for (int ct = 0; ct < 2; ++ct)
          bf[(u + 1) & 1][ks * 2 + ct] = *(const f16x8*)(nb + ks * 4096 + ct * 512);
      __builtin_amdgcn_s_setprio(1);
#pragma unroll
      for (int ks = 0; ks < 4; ++ks)
#pragma unroll
        for (int rt = 0; rt < 2; ++rt) {
          f16x8 af = xv[rt][ks] * as8[rt][u];
#pragma unroll
          for (int ct = 0; ct < 2; ++ct)
            acc[rt][ct] = __builtin_amdgcn_mfma_f32_32x32x16_f16(af, bf[u & 1][ks * 2 + ct], acc[rt][ct], 0, 0, 0);
        }
      __builtin_amdgcn_s_setprio(0);
      char* t = p0; p0 = p1; p1 = p2; p2 = t;
    }
  }

  // bias chunk (q=256): bf[0] holds it (prefetched at the last iteration).
#pragma unroll
  for (int ks = 0; ks < 4; ++ks)
#pragma unroll
    for (int rt = 0; rt < 2; ++rt) {
      f16x8 af = *(const f16x8*)((const char*)sAa + (wr * 64 + rt * 32 + l31) * 144
                                 + ks * 32 + khalf * 16);
#pragma unroll
      for (int ct = 0; ct < 2; ++ct)
        acc[rt][ct] = __builtin_amdgcn_mfma_f32_32x32x16_f16(af, bf[0][ks * 2 + ct], acc[rt][ct], 0, 0, 0);
    }

  // store: row = rb*128 + wr*64 + rt*32 + (r&3)+8*(r>>2)+4*khalf;
  //        col = cb*128 + wc*64 + ct*32 + l31
#pragma unroll
  for (int rt = 0; rt < 2; ++rt)
#pragma unroll
    for (int ct = 0; ct < 2; ++ct)
#pragma unroll
      for (int r = 0; r < 16; ++r) {
        int rowin = (r & 3) + 8 * (r >> 2) + 4 * khalf;
        size_t row = (size_t)rb * 128 + wr * 64 + rt * 32 + rowin;
        int col = cb * 128 + wc * 64 + ct * 32 + l31;
        sel[row * 256 + col] = (f16)acc[rt][ct][r];
      }
}

// ---------------------------------------------------------------------------
extern "C" void kernel_launch(void* const* d_in, const int* in_sizes, int n_in,
                              void* d_out, int out_size, void* d_ws, size_t ws_size,
                              hipStream_t stream) {
  (void)in_sizes; (void)n_in; (void)out_size;
  const float* x   = (const float*)d_in[0];
  const float* ctx = (const float*)d_in[1];
  const float* Wm  = (const float*)d_in[2];
  const float* bm  = (const float*)d_in[3];
  const float* cm  = (const float*)d_in[4];
  const float* um  = (const float*)d_in[5];
  const float* vm  = (const float*)d_in[6];
  const float* W1  = (const float*)d_in[7];
  const float* b1  = (const float*)d_in[8];
  const float* W2  = (const float*)d_in[9];
  const float* b2  = (const float*)d_in[10];
  const float* Wi  = (const float*)d_in[11];
  const float* bi  = (const float*)d_in[12];
  float* out = (float*)d_out;

  char* ws = (char*)d_ws;
  size_t off = 0;
  // Wcat: 2 col-halves x 260 sub-chunk slots x 16KB (257 real + dummy tail)
  f16* Wcat = (f16*)(ws + off); off += (size_t)2 * 260 * 8192 * 2;
  f16* W1t  = (f16*)(ws + off); off += (size_t)512 * 256 * 2;
  f16* W2t  = (f16*)(ws + off); off += (size_t)64 * 512 * 2;
  f16* umt  = (f16*)(ws + off); off += (size_t)64 * 256 * 2;
  f16* Wit  = (f16*)(ws + off); off += (size_t)256 * 512 * 2;
  f16* h16  = (f16*)(ws + off); off += (size_t)32768 * 512 * 2;
  float* logits = (float*)(ws + off); off += (size_t)32768 * 64 * 4;
  float* glog   = (float*)(ws + off); off += (size_t)32768 * 64 * 4;
  f16* a16   = (f16*)(ws + off); off += (size_t)32768 * 64 * 2;
  f16* sel16 = (f16*)(ws + off); off += (size_t)32768 * 256 * 2;
  if (ws_size < off) return;

  // ---- weight prep ----
  prep_wcat_kernel<<<dim3(2056), dim3(256), 0, stream>>>(Wm, bm, cm, Wcat);
  prep_b_kernel<<<dim3(16384 / 256), dim3(256), 0, stream>>>(W1, W1t, 256, 256, 16384);
  prep_b_kernel<<<dim3(4096 / 256),  dim3(256), 0, stream>>>(W2, W2t, 512, 64, 4096);
  prep_b_kernel<<<dim3(2048 / 256),  dim3(256), 0, stream>>>(um, umt, 256, 64, 2048);
  prep_b_kernel<<<dim3(16384 / 256), dim3(256), 0, stream>>>(Wi, Wit, 512, 256, 16384);

  // ---- phase A: selector ----
  gemm_tpl<256, 4, 4, 1><<<dim3(256, 2), dim3(512), 0, stream>>>(
      ctx, 256, nullptr, 0, W1t, b1, nullptr, h16, 512);
  gemm_tpl<64, 4, 4, 0><<<dim3(256, 1), dim3(256), 0, stream>>>(
      x, 256, nullptr, 0, umt, nullptr, glog, nullptr, 64);
  gemm_tpl<64, 8, 0, 0><<<dim3(256, 1), dim3(256), 0, stream>>>(
      nullptr, 0, h16, 512, W2t, nullptr, logits, nullptr, 64);
  selector_finish<<<dim3(32768 / 4), dim3(256), 0, stream>>>(logits, glog, b2, vm, a16);

  // ---- phase B: the 275-TFLOP contraction ----
  big_gemm<<<dim3(256, 2), dim3(256), 0, stream>>>(x, a16, Wcat, sel16);

  // ---- phase C: integrate([x, selected]) ----
  gemm_tpl<256, 8, 4, 0><<<dim3(256, 1), dim3(512), 0, stream>>>(
      x, 256, sel16, 256, Wit, bi, out, nullptr, 256);
}